// Round 6
// baseline (214.890 us; speedup 1.0000x reference)
//
#include <hip/hip_runtime.h>
#include <hip/hip_fp16.h>
#include <math.h>

// Problem constants
#define HID   1024
#define NHEAD 16
#define HD    64
#define NB    64
#define MAXS  2048
#define CH    64                      // positions per attn block
#define NCH   (MAXS / CH)             // 32
#define PS    68                      // floats per (c,b,h) partial record

// ---------------------------------------------------------------------------
// Kernel 1: fused projections (unchanged — W read exactly once)
// ---------------------------------------------------------------------------
__global__ __launch_bounds__(1024) void proj_kernel(
    const float* __restrict__ seq, const float* __restrict__ cand,
    const float* __restrict__ Wqkv, const float* __restrict__ bqkv,
    const float* __restrict__ Wc,   const float* __restrict__ bcv,
    float* __restrict__ out /* [4096][64] col-major */)
{
    const int tid  = threadIdx.x;
    const int wv   = __builtin_amdgcn_readfirstlane(tid >> 6);
    const int lane = tid & 63;
    const int c0   = blockIdx.x * 16;
    const bool is_qkv = (c0 < 3072);
    const float* __restrict__ src  = is_qkv ? seq  : cand;
    const float* __restrict__ W    = is_qkv ? Wqkv : Wc;
    const float* __restrict__ bias = is_qkv ? bqkv : bcv;
    const int ldw = is_qkv ? 3072 : 1024;
    const int cb  = is_qkv ? c0 : (c0 - 3072);
    const int k0  = wv * 64;

    float acc[16];
    #pragma unroll
    for (int j = 0; j < 16; ++j) acc[j] = 0.f;

    const float4* sp = (const float4*)(src + lane * HID + k0);
    for (int kc = 0; kc < 16; ++kc) {
        float4 s4 = sp[kc];
        const float* wb = W + (size_t)(k0 + kc * 4) * ldw + cb;
        #pragma unroll
        for (int t = 0; t < 4; ++t) {
            float sv = (t == 0) ? s4.x : (t == 1) ? s4.y : (t == 2) ? s4.z : s4.w;
            const float4* wr = (const float4*)(wb + (size_t)t * ldw);
            #pragma unroll
            for (int j = 0; j < 4; ++j) {
                float4 w4 = wr[j];
                acc[4*j+0] = fmaf(sv, w4.x, acc[4*j+0]);
                acc[4*j+1] = fmaf(sv, w4.y, acc[4*j+1]);
                acc[4*j+2] = fmaf(sv, w4.z, acc[4*j+2]);
                acc[4*j+3] = fmaf(sv, w4.w, acc[4*j+3]);
            }
        }
    }

    __shared__ float red[16][16][64];
    #pragma unroll
    for (int j = 0; j < 16; ++j) red[wv][j][lane] = acc[j];
    __syncthreads();

    {
        const int j = tid >> 6, b = tid & 63;
        float s = 0.f;
        #pragma unroll
        for (int w = 0; w < 16; ++w) s += red[w][j][b];
        out[(c0 + j) * 64 + b] = s + bias[cb + j];
    }
}

// ---------------------------------------------------------------------------
// Kernel 2a: DENSE-ROW two-phase attention partials.
// Block (c, b) owns positions [c*64, c*64+63] ∩ [0,L] for ALL 16 heads.
// Thread tid -> (h = tid>>4, gl = tid&15) = float4 at byte offset tid*16 of
// each 4 KB row: every row read is 4x 1KB-contiguous wave loads (dense).
// Phase 1: stream k rows -> per-head scores into LDS (16-lane reduce, no
//   cross-position dependency). Per-head softmax from LDS (wave-local).
// Phase 2: stream v rows -> o accumulation. New token (pos L) handled from
//   registers (thread (h,gl) computes exactly its own row fragment).
// No __syncthreads: score column h is written and read only by h's wave.
// ---------------------------------------------------------------------------
__global__ __launch_bounds__(256) void attn_part_kernel(
    const float* __restrict__ proj, const float* __restrict__ k_cache,
    const float* __restrict__ v_cache, const int* __restrict__ seqlens,
    float* __restrict__ part)
{
    const int idx = blockIdx.x;
    const int c = idx >> 6;            // chunk slowest
    const int b = idx & 63;
    const int L = seqlens[b];
    const int s0 = c << 6;
    if (s0 > L) return;

    const int tid = threadIdx.x;
    const int h   = tid >> 4;
    const int gl  = tid & 15;
    const int ncache  = min(CH, L - s0);        // cache rows (pos L is NOT from cache)
    const bool has_new = (L < s0 + CH);
    const int nv = ncache + (has_new ? 1 : 0);  // >= 1 always

    __shared__ float sc[CH + 1][16];            // [row][head] scores -> probs

    // q fragment (h, dims gl*4..gl*4+3)
    float4 q4;
    {
        const float* qp = proj + (h * 192 + gl * 4) * 64 + b;
        q4.x = qp[0]; q4.y = qp[64]; q4.z = qp[128]; q4.w = qp[192];
    }

    // new-token k (normalize + fp16 round) and v, in registers:
    // thread (h,gl) computes exactly the row fragment it consumes.
    float4 kn4 = make_float4(0.f,0.f,0.f,0.f), vn4 = make_float4(0.f,0.f,0.f,0.f);
    if (has_new) {
        const float* kp = proj + (h * 192 + 64 + gl * 4) * 64 + b;
        float4 kr; kr.x = kp[0]; kr.y = kp[64]; kr.z = kp[128]; kr.w = kp[192];
        float ss = kr.x*kr.x + kr.y*kr.y + kr.z*kr.z + kr.w*kr.w;
        ss += __shfl_xor(ss, 1); ss += __shfl_xor(ss, 2);
        ss += __shfl_xor(ss, 4); ss += __shfl_xor(ss, 8);
        float inv = 1.f / sqrtf(ss);
        kn4.x = __half2float(__float2half_rn(kr.x * inv));
        kn4.y = __half2float(__float2half_rn(kr.y * inv));
        kn4.z = __half2float(__float2half_rn(kr.z * inv));
        kn4.w = __half2float(__float2half_rn(kr.w * inv));
        const float* vp = proj + (h * 192 + 128 + gl * 4) * 64 + b;
        vn4.x = vp[0]; vn4.y = vp[64]; vn4.z = vp[128]; vn4.w = vp[192];
    }

    // ---- Phase 1: dense K stream ----
    const float4* krow = (const float4*)(k_cache + ((size_t)b * MAXS + s0) * (NHEAD * HD));
    #pragma unroll 8
    for (int t = 0; t < ncache; ++t) {
        float4 k4 = krow[t * 256 + tid];
        float d = fmaf(k4.x, q4.x, fmaf(k4.y, q4.y, fmaf(k4.z, q4.z, k4.w * q4.w)));
        d += __shfl_xor(d, 1); d += __shfl_xor(d, 2);
        d += __shfl_xor(d, 4); d += __shfl_xor(d, 8);
        if (gl == 0) sc[t][h] = d;
    }
    if (has_new) {
        float d = fmaf(kn4.x, q4.x, fmaf(kn4.y, q4.y, fmaf(kn4.z, q4.z, kn4.w * q4.w)));
        d += __shfl_xor(d, 1); d += __shfl_xor(d, 2);
        d += __shfl_xor(d, 4); d += __shfl_xor(d, 8);
        if (gl == 0) sc[ncache][h] = d;
    }

    // ---- per-head softmax over nv entries (wave-local; lanes redundant) ----
    float m = -INFINITY;
    for (int t = 0; t < nv; ++t) m = fmaxf(m, sc[t][h]);
    float l = 0.f;
    for (int t = 0; t < nv; ++t) {
        float p = __expf(sc[t][h] - m);   // read-before-write within wave: safe
        l += p;
        if (gl == 0) sc[t][h] = p;        // overwrite score with prob
    }

    // ---- Phase 2: dense V stream ----
    float4 o = make_float4(0.f, 0.f, 0.f, 0.f);
    const float4* vrow = (const float4*)(v_cache + ((size_t)b * MAXS + s0) * (NHEAD * HD));
    #pragma unroll 8
    for (int t = 0; t < ncache; ++t) {
        float4 v4 = vrow[t * 256 + tid];
        float p = sc[t][h];
        o.x = fmaf(p, v4.x, o.x);
        o.y = fmaf(p, v4.y, o.y);
        o.z = fmaf(p, v4.z, o.z);
        o.w = fmaf(p, v4.w, o.w);
    }
    if (has_new) {
        float p = sc[ncache][h];
        o.x = fmaf(p, vn4.x, o.x);
        o.y = fmaf(p, vn4.y, o.y);
        o.z = fmaf(p, vn4.z, o.z);
        o.w = fmaf(p, vn4.w, o.w);
    }

    float* pb = part + (size_t)((c * 64 + b) * 16 + h) * PS;
    ((float4*)pb)[gl] = o;
    if (gl == 0) { pb[64] = m; pb[65] = l; }
}

// ---------------------------------------------------------------------------
// Kernel 2b: merge <=32 chunk partials per (b,h). 1024 blocks x 64 threads.
// ---------------------------------------------------------------------------
__global__ __launch_bounds__(64) void attn_merge_kernel(
    const float* __restrict__ part, const int* __restrict__ seqlens,
    float* __restrict__ attn_out /* [1024][64] col-major */)
{
    const int bh = blockIdx.x;
    const int b  = bh >> 4;
    const int h  = bh & 15;
    const int d  = threadIdx.x;
    const int nch = (seqlens[b] >> 6) + 1;

    float M = -INFINITY, l = 0.f, o = 0.f;
    for (int c = 0; c < nch; ++c) {
        const float* pb = part + (size_t)((c * 64 + b) * 16 + h) * PS;
        float mc = pb[64], lc = pb[65];
        float Mn = fmaxf(M, mc);
        float f = __expf(M - Mn);
        float w = __expf(mc - Mn);
        o = o * f + w * pb[d];
        l = l * f + w * lc;
        M = Mn;
    }
    attn_out[(h * 64 + d) * 64 + b] = o / l;
}

// ---------------------------------------------------------------------------
// Kernel 3: postx = attn @ Wo + bo (unchanged)
// ---------------------------------------------------------------------------
__global__ __launch_bounds__(1024) void wo_kernel(
    const float* __restrict__ attn_s, const float* __restrict__ Wo,
    const float* __restrict__ bo, float* __restrict__ postx /* [1024][64] */)
{
    const int tid  = threadIdx.x;
    const int wv   = __builtin_amdgcn_readfirstlane(tid >> 6);
    const int lane = tid & 63;
    const int c0   = blockIdx.x * 8;
    const int k0   = wv * 64;

    float acc[8];
    #pragma unroll
    for (int j = 0; j < 8; ++j) acc[j] = 0.f;

    for (int k = 0; k < 64; ++k) {
        float sv = attn_s[(k0 + k) * 64 + lane];
        const float4* wr = (const float4*)(Wo + (size_t)(k0 + k) * 1024 + c0);
        float4 w0 = wr[0], w1 = wr[1];
        acc[0] = fmaf(sv, w0.x, acc[0]); acc[1] = fmaf(sv, w0.y, acc[1]);
        acc[2] = fmaf(sv, w0.z, acc[2]); acc[3] = fmaf(sv, w0.w, acc[3]);
        acc[4] = fmaf(sv, w1.x, acc[4]); acc[5] = fmaf(sv, w1.y, acc[5]);
        acc[6] = fmaf(sv, w1.z, acc[6]); acc[7] = fmaf(sv, w1.w, acc[7]);
    }

    __shared__ float red[16][8][64];
    #pragma unroll
    for (int j = 0; j < 8; ++j) red[wv][j][lane] = acc[j];
    __syncthreads();

    if (tid < 512) {
        const int j = tid >> 6, b = tid & 63;
        float s = 0.f;
        #pragma unroll
        for (int w = 0; w < 16; ++w) s += red[w][j][b];
        postx[(c0 + j) * 64 + b] = s + bo[c0 + j];
    }
}

// ---------------------------------------------------------------------------
// Kernel 4: dual LayerNorm (unchanged)
// ---------------------------------------------------------------------------
__global__ __launch_bounds__(256) void ln_kernel(
    const float* __restrict__ seq, const float* __restrict__ cand_s,
    const float* __restrict__ postx, const float* __restrict__ gamma,
    const float* __restrict__ beta, float* __restrict__ out)
{
    const int b   = blockIdx.x;
    const int tid = threadIdx.x;
    float x1[4], x2[4];
    float s1 = 0.f, q1 = 0.f, s2 = 0.f, q2 = 0.f;

    #pragma unroll
    for (int i = 0; i < 4; ++i) {
        int c = tid + i * 256;
        float px = postx[c * 64 + b];
        float sv = seq[b * HID + c];
        float cd = cand_s[c * 64 + b];
        float a = sv + px, d = px + cd;
        x1[i] = a; x2[i] = d;
        s1 += a; q1 += a * a; s2 += d; q2 += d * d;
    }
    #pragma unroll
    for (int m = 1; m < 64; m <<= 1) {
        s1 += __shfl_xor(s1, m); q1 += __shfl_xor(q1, m);
        s2 += __shfl_xor(s2, m); q2 += __shfl_xor(q2, m);
    }
    __shared__ float rsm[4][4];
    const int wv = tid >> 6, lane = tid & 63;
    if (lane == 0) { rsm[wv][0] = s1; rsm[wv][1] = q1; rsm[wv][2] = s2; rsm[wv][3] = q2; }
    __syncthreads();

    float S1 = rsm[0][0] + rsm[1][0] + rsm[2][0] + rsm[3][0];
    float Q1 = rsm[0][1] + rsm[1][1] + rsm[2][1] + rsm[3][1];
    float S2 = rsm[0][2] + rsm[1][2] + rsm[2][2] + rsm[3][2];
    float Q2 = rsm[0][3] + rsm[1][3] + rsm[2][3] + rsm[3][3];

    const float inv = 1.f / 1024.f;
    float mu1 = S1 * inv, v1 = Q1 * inv - mu1 * mu1;
    float mu2 = S2 * inv, v2 = Q2 * inv - mu2 * mu2;
    float r1 = rsqrtf(v1 + 1e-5f);
    float r2 = rsqrtf(v2 + 1e-5f);

    #pragma unroll
    for (int i = 0; i < 4; ++i) {
        int c = tid + i * 256;
        float g = gamma[c], be = beta[c];
        out[b * HID + c]            = (x1[i] - mu1) * r1 * g + be;   // seq_out
        out[NB * HID + b * HID + c] = (x2[i] - mu2) * r2 * g + be;   // candidate_out
    }
}

// ---------------------------------------------------------------------------
extern "C" void kernel_launch(void* const* d_in, const int* in_sizes, int n_in,
                              void* d_out, int out_size, void* d_ws, size_t ws_size,
                              hipStream_t stream) {
    const float* seq      = (const float*)d_in[0];
    const float* cand     = (const float*)d_in[1];
    const float* k_cache  = (const float*)d_in[2];
    const float* v_cache  = (const float*)d_in[3];
    const int*   seqlens  = (const int*)  d_in[4];
    const float* Wqkv     = (const float*)d_in[5];
    const float* bqkv     = (const float*)d_in[6];
    const float* Wc       = (const float*)d_in[7];
    const float* bcv      = (const float*)d_in[8];
    const float* Wo       = (const float*)d_in[9];
    const float* bo       = (const float*)d_in[10];
    const float* gamma    = (const float*)d_in[11];
    const float* beta     = (const float*)d_in[12];
    float* out = (float*)d_out;

    float* ws    = (float*)d_ws;
    float* proj  = ws;                         // [4096][64] = 262144 f
    float* attn  = proj  + 4096 * 64;          // [1024][64] =  65536 f
    float* postx = attn  + 1024 * 64;          // [1024][64] =  65536 f
    float* part  = postx + 1024 * 64;          // [32*64*16][PS] = 2228224 f (~8.9 MB)

    proj_kernel      <<<256, 1024, 0, stream>>>(seq, cand, Wqkv, bqkv, Wc, bcv, proj);
    attn_part_kernel <<<NCH * NB, 256, 0, stream>>>(proj, k_cache, v_cache, seqlens, part);
    attn_merge_kernel<<<NB * NHEAD, 64, 0, stream>>>(part, seqlens, attn);
    wo_kernel        <<<128, 1024, 0, stream>>>(attn, Wo, bo, postx);
    ln_kernel        <<<NB, 256, 0, stream>>>(seq, proj + 3072 * 64, postx, gamma, beta, out);
}